// Round 5
// baseline (194.915 us; speedup 1.0000x reference)
//
#include <hip/hip_runtime.h>
#include <hip/hip_bf16.h>
#include <math.h>

#define KROWS 8192
#define DDIM  128
#define RT    128            // rows per block (4 waves x 32 rows)
#define CTILE 64             // cols per tile
#define NTILES (KROWS / CTILE)   // 128
#define NCB   16             // col-block count (grid = 64*16 = 1024 = 4/CU)
#define NITER (NTILES / NCB) // 8 tiles per block
#define TILEB (CTILE * DDIM * 2)   // 16384 bytes per Y tile
#define SHIFT 94.0f          // fixed log2-domain shift (logits in [-300,-90])

static constexpr float LOG2E_F = 1.44269504088896340736f;
static constexpr float LN2_F   = 0.69314718055994530942f;

typedef __attribute__((ext_vector_type(8))) short short8;   // 8 bf16
typedef __attribute__((ext_vector_type(4))) float float4v;  // 4 fp32 acc

#if __has_builtin(__builtin_amdgcn_exp2f)
#define EXP2(x) __builtin_amdgcn_exp2f(x)
#else
#define EXP2(x) exp2f(x)
#endif

#define AS1C(p) ((const __attribute__((address_space(1))) void*)(p))
#define AS3(p)  ((__attribute__((address_space(3))) void*)(p))

static __device__ __forceinline__ unsigned short f2bf(float f) {
    __hip_bfloat16 h = __float2bfloat16(f);
    return *reinterpret_cast<unsigned short*>(&h);
}

// Kernel 1: bf16 casts (X pre-scaled by log2e), fp32 row terms, exact fp32
// diagonal logits. One wave per row, 4 rows/block. Also zero-inits pl.
__global__ __launch_bounds__(256) void prep_kernel(
    const float* __restrict__ x, const float* __restrict__ y,
    unsigned int* __restrict__ xb, unsigned int* __restrict__ yb,
    float* __restrict__ xsq2, float* __restrict__ ysq2,
    float* __restrict__ diagn, float* __restrict__ pl)
{
    const int w = threadIdx.x >> 6, lane = threadIdx.x & 63;
    const int row = blockIdx.x * 4 + w;
    if (blockIdx.x < KROWS / 256) pl[blockIdx.x * 256 + threadIdx.x] = 0.0f;
    const float2 xv = *reinterpret_cast<const float2*>(x + (size_t)row * DDIM + lane * 2);
    const float2 yv = *reinterpret_cast<const float2*>(y + (size_t)row * DDIM + lane * 2);
    xb[(size_t)row * 64 + lane] = (unsigned int)f2bf(xv.x * LOG2E_F)
                                | ((unsigned int)f2bf(xv.y * LOG2E_F) << 16);
    yb[(size_t)row * 64 + lane] = (unsigned int)f2bf(yv.x) | ((unsigned int)f2bf(yv.y) << 16);
    float xx = xv.x * xv.x + xv.y * xv.y;
    float yy = yv.x * yv.x + yv.y * yv.y;
    float xy = xv.x * yv.x + xv.y * yv.y;
    #pragma unroll
    for (int o = 32; o > 0; o >>= 1) {
        xx += __shfl_xor(xx, o, 64);
        yy += __shfl_xor(yy, o, 64);
        xy += __shfl_xor(xy, o, 64);
    }
    if (lane == 0) {
        xsq2[row] = fmaf(-0.5f * xx, LOG2E_F, SHIFT);   // log2 row term + shift (fp32)
        ysq2[row] = -0.5f * yy * LOG2E_F;               // log2 col term (fp32)
        diagn[row] = xy - 0.5f * (xx + yy);             // natural-log diag logit (fp32 exact)
    }
}

// Kernel 2: fused bf16 MFMA GEMM + shifted sum-of-exp2.
// Double-buffered LDS; DMA prefetch for tile k+1 issued BEFORE the MFMA phase
// of tile k -> one barrier per tile, DMA latency hidden under compute.
// Grid 1024 = (rb = b&63, c0 = b>>6); block handles tiles ct = c0 + 16k.
__global__ __launch_bounds__(256, 4) void gemm_lse_kernel(
    const unsigned short* __restrict__ xb, const unsigned short* __restrict__ yb,
    const float* __restrict__ xsq2, const float* __restrict__ ysq2,
    float* __restrict__ pl)
{
    __shared__ alignas(16) unsigned char Ys[2][TILEB];   // 2 x 16 KB, linear (DMA target)

    const int t = threadIdx.x;
    const int w = t >> 6, lane = t & 63, quad = lane >> 4, lo = lane & 15;
    const int rb = (blockIdx.x & 63) * RT;
    const int c0 = blockIdx.x >> 6;    // [0,16)

    // Persistent A fragments (X rows, log2e pre-scaled), from global once.
    short8 af[2][4];
    #pragma unroll
    for (int ri = 0; ri < 2; ri++)
        #pragma unroll
        for (int kk = 0; kk < 4; kk++)
            af[ri][kk] = *reinterpret_cast<const short8*>(
                xb + (size_t)(rb + w * 32 + ri * 16 + lo) * DDIM + kk * 32 + quad * 8);

    // Row terms (log2 domain, SHIFT included).
    float a2v[8];
    #pragma unroll
    for (int ri = 0; ri < 2; ri++)
        #pragma unroll
        for (int r = 0; r < 4; r++)
            a2v[ri * 4 + r] = xsq2[rb + w * 32 + ri * 16 + quad * 4 + r];

    float sums[8];
    #pragma unroll
    for (int i = 0; i < 8; i++) sums[i] = 0.0f;

    // Staging swizzle: LDS unit i <- global unit (row=i>>4, u=(i&15)^(row&7)).
    const int gswz = ((t >> 4) << 8) + (((t & 15) ^ ((t >> 4) & 7)) << 4);
    // Read bases: data for (col c, K-seg s) sits at c*256 + (s^(c&7))*16.
    int base_k[4];
    #pragma unroll
    for (int kk = 0; kk < 4; kk++)
        base_k[kk] = lo * 256 + ((((kk << 2) + quad) ^ (lo & 7)) << 4);

    // Stage tile 0 into buf 0.
    {
        const char* g = (const char*)yb + (size_t)c0 * TILEB + gswz;
        #pragma unroll
        for (int q = 0; q < 4; q++)
            __builtin_amdgcn_global_load_lds(AS1C(g + q * 4096),
                                             AS3(&Ys[0][(q * 256 + t) * 16]), 16, 0, 0);
    }
    __syncthreads();

    #pragma unroll
    for (int k = 0; k < NITER; k++) {
        const int ct = c0 + k * NCB;

        // Prefetch tile k+1 into the other buffer (latency hides under MFMA).
        if (k + 1 < NITER) {
            const char* g = (const char*)yb + (size_t)(ct + NCB) * TILEB + gswz;
            #pragma unroll
            for (int q = 0; q < 4; q++)
                __builtin_amdgcn_global_load_lds(AS1C(g + q * 4096),
                                                 AS3(&Ys[(k + 1) & 1][(q * 256 + t) * 16]), 16, 0, 0);
        }

        // Col terms for this tile (fp32).
        float b2[4];
        #pragma unroll
        for (int ci = 0; ci < 4; ci++) b2[ci] = ysq2[ct * CTILE + ci * 16 + lo];

        // Init acc with per-output constant via the MFMA C operand.
        float4v acc[2][4];
        #pragma unroll
        for (int ri = 0; ri < 2; ri++)
            #pragma unroll
            for (int ci = 0; ci < 4; ci++)
                acc[ri][ci] = (float4v){a2v[ri * 4 + 0] + b2[ci], a2v[ri * 4 + 1] + b2[ci],
                                        a2v[ri * 4 + 2] + b2[ci], a2v[ri * 4 + 3] + b2[ci]};

        #pragma unroll
        for (int kk = 0; kk < 4; kk++) {
            #pragma unroll
            for (int ci = 0; ci < 4; ci++) {
                short8 b = *reinterpret_cast<const short8*>(&Ys[k & 1][base_k[kk] + ci * 4096]);
                acc[0][ci] = __builtin_amdgcn_mfma_f32_16x16x32_bf16(af[0][kk], b, acc[0][ci], 0, 0, 0);
                acc[1][ci] = __builtin_amdgcn_mfma_f32_16x16x32_bf16(af[1][kk], b, acc[1][ci], 0, 0, 0);
            }
        }

        // Epilogue: one v_exp_f32 + one add per output (register-only).
        #pragma unroll
        for (int ri = 0; ri < 2; ri++)
            #pragma unroll
            for (int r = 0; r < 4; r++) {
                float s = 0.0f;
                #pragma unroll
                for (int ci = 0; ci < 4; ci++)
                    s += EXP2(acc[ri][ci][r]);
                sums[ri * 4 + r] += s;
            }

        // Single barrier per tile: separates this tile's buf readers from the
        // next DMA write, and drains vmcnt so the prefetched buf is ready.
        __syncthreads();
    }

    // Flush: reduce the 16 lanes sharing each row, one atomicAdd per row.
    #pragma unroll
    for (int i = 0; i < 8; i++) {
        float s = sums[i];
        s += __shfl_xor(s, 1, 64);
        s += __shfl_xor(s, 2, 64);
        s += __shfl_xor(s, 4, 64);
        s += __shfl_xor(s, 8, 64);
        if (lo == 0) {
            int row = rb + w * 32 + (i >> 2) * 16 + quad * 4 + (i & 3);
            atomicAdd(&pl[row], s);
        }
    }
}

// Kernel 3: row losses from accumulated sums -> mean. Single block.
__global__ __launch_bounds__(1024) void finish_kernel(
    const float* __restrict__ pl, const float* __restrict__ diagn,
    float* __restrict__ out)
{
    const int t = threadIdx.x;
    float acc = 0.0f;
    for (int r = t; r < KROWS; r += 1024)
        acc += (log2f(pl[r]) - SHIFT) * LN2_F - diagn[r];
    #pragma unroll
    for (int o = 32; o > 0; o >>= 1) acc += __shfl_down(acc, o, 64);
    __shared__ float ws[16];
    if ((t & 63) == 0) ws[t >> 6] = acc;
    __syncthreads();
    if (t == 0) {
        float s = 0.0f;
        #pragma unroll
        for (int i = 0; i < 16; i++) s += ws[i];
        out[0] = s * (1.0f / KROWS);
    }
}

extern "C" void kernel_launch(void* const* d_in, const int* in_sizes, int n_in,
                              void* d_out, int out_size, void* d_ws, size_t ws_size,
                              hipStream_t stream) {
    const float* x = (const float*)d_in[0];   // features_nc
    const float* y = (const float*)d_in[1];   // features_c
    float* out = (float*)d_out;

    // Workspace layout (~4.2 MB)
    unsigned short* xb = (unsigned short*)d_ws;            // K*D bf16 (2 MB)
    unsigned short* yb = xb + (size_t)KROWS * DDIM;        // K*D bf16 (2 MB)
    float* xsq2  = (float*)(yb + (size_t)KROWS * DDIM);    // K
    float* ysq2  = xsq2 + KROWS;                           // K
    float* diagn = ysq2 + KROWS;                           // K
    float* pl    = diagn + KROWS;                          // K (row sum-of-exp2)

    prep_kernel<<<KROWS / 4, 256, 0, stream>>>(x, y, (unsigned int*)xb, (unsigned int*)yb,
                                               xsq2, ysq2, diagn, pl);
    gemm_lse_kernel<<<64 * NCB, 256, 0, stream>>>(xb, yb, xsq2, ysq2, pl);
    finish_kernel<<<1, 1024, 0, stream>>>(pl, diagn, out);
}

// Round 6
// 110.811 us; speedup vs baseline: 1.7590x; 1.7590x over previous
//
#include <hip/hip_runtime.h>
#include <hip/hip_bf16.h>
#include <math.h>

#define KROWS 8192
#define DDIM  128
#define RT    128            // rows per block (4 waves x 32 rows)
#define CTILE 64             // cols per tile
#define NTILES (KROWS / CTILE)   // 128
#define NCB   16             // col-block count (grid = 64*16 = 1024 = 4/CU)
#define NITER (NTILES / NCB) // 8 tiles per block
#define TILEB (CTILE * DDIM * 2)   // 16384 bytes per Y tile
#define SHIFT 94.0f          // fixed log2-domain shift (logits in [-300,-90])

static constexpr float LOG2E_F = 1.44269504088896340736f;
static constexpr float LN2_F   = 0.69314718055994530942f;

typedef __attribute__((ext_vector_type(8))) short short8;   // 8 bf16
typedef __attribute__((ext_vector_type(4))) float float4v;  // 4 fp32 acc

#if __has_builtin(__builtin_amdgcn_exp2f)
#define EXP2(x) __builtin_amdgcn_exp2f(x)
#else
#define EXP2(x) exp2f(x)
#endif

#define AS1C(p) ((const __attribute__((address_space(1))) void*)(p))
#define AS3(p)  ((__attribute__((address_space(3))) void*)(p))

static __device__ __forceinline__ unsigned short f2bf(float f) {
    __hip_bfloat16 h = __float2bfloat16(f);
    return *reinterpret_cast<unsigned short*>(&h);
}

// Kernel 1: bf16 casts (X pre-scaled by log2e), fp32 row terms, exact fp32
// diagonal logits. One wave per row, 4 rows/block. Also zero-inits pl.
__global__ __launch_bounds__(256) void prep_kernel(
    const float* __restrict__ x, const float* __restrict__ y,
    unsigned int* __restrict__ xb, unsigned int* __restrict__ yb,
    float* __restrict__ xsq2, float* __restrict__ ysq2,
    float* __restrict__ diagn, float* __restrict__ pl)
{
    const int w = threadIdx.x >> 6, lane = threadIdx.x & 63;
    const int row = blockIdx.x * 4 + w;
    if (blockIdx.x < KROWS / 256) pl[blockIdx.x * 256 + threadIdx.x] = 0.0f;
    const float2 xv = *reinterpret_cast<const float2*>(x + (size_t)row * DDIM + lane * 2);
    const float2 yv = *reinterpret_cast<const float2*>(y + (size_t)row * DDIM + lane * 2);
    xb[(size_t)row * 64 + lane] = (unsigned int)f2bf(xv.x * LOG2E_F)
                                | ((unsigned int)f2bf(xv.y * LOG2E_F) << 16);
    yb[(size_t)row * 64 + lane] = (unsigned int)f2bf(yv.x) | ((unsigned int)f2bf(yv.y) << 16);
    float xx = xv.x * xv.x + xv.y * xv.y;
    float yy = yv.x * yv.x + yv.y * yv.y;
    float xy = xv.x * yv.x + xv.y * yv.y;
    #pragma unroll
    for (int o = 32; o > 0; o >>= 1) {
        xx += __shfl_xor(xx, o, 64);
        yy += __shfl_xor(yy, o, 64);
        xy += __shfl_xor(xy, o, 64);
    }
    if (lane == 0) {
        xsq2[row] = fmaf(-0.5f * xx, LOG2E_F, SHIFT);   // log2 row term + shift (fp32)
        ysq2[row] = -0.5f * yy * LOG2E_F;               // log2 col term (fp32)
        diagn[row] = xy - 0.5f * (xx + yy);             // natural-log diag logit (fp32 exact)
    }
}

// Kernel 2: fused bf16 MFMA GEMM + shifted sum-of-exp2.
// Double-buffered LDS; DMA prefetch for tile k+1 issued BEFORE the MFMA phase
// of tile k -> one barrier per tile, DMA latency hidden under compute.
// Grid 1024 = (rb = b&63, c0 = b>>6); block handles tiles ct = c0 + 16k.
// NOTE: __launch_bounds__ second arg must stay 2 — (256,4) caps this kernel
// at 64 VGPRs on this toolchain and forces catastrophic scratch spill
// (measured twice: rounds 3 and 5, FETCH/WRITE 150-380 MB).
__global__ __launch_bounds__(256, 2) void gemm_lse_kernel(
    const unsigned short* __restrict__ xb, const unsigned short* __restrict__ yb,
    const float* __restrict__ xsq2, const float* __restrict__ ysq2,
    float* __restrict__ pl)
{
    __shared__ alignas(16) unsigned char Ys[2][TILEB];   // 2 x 16 KB, linear (DMA target)

    const int t = threadIdx.x;
    const int w = t >> 6, lane = t & 63, quad = lane >> 4, lo = lane & 15;
    const int rb = (blockIdx.x & 63) * RT;
    const int c0 = blockIdx.x >> 6;    // [0,16)

    // Persistent A fragments (X rows, log2e pre-scaled), from global once.
    short8 af[2][4];
    #pragma unroll
    for (int ri = 0; ri < 2; ri++)
        #pragma unroll
        for (int kk = 0; kk < 4; kk++)
            af[ri][kk] = *reinterpret_cast<const short8*>(
                xb + (size_t)(rb + w * 32 + ri * 16 + lo) * DDIM + kk * 32 + quad * 8);

    // Row terms (log2 domain, SHIFT included).
    float a2v[8];
    #pragma unroll
    for (int ri = 0; ri < 2; ri++)
        #pragma unroll
        for (int r = 0; r < 4; r++)
            a2v[ri * 4 + r] = xsq2[rb + w * 32 + ri * 16 + quad * 4 + r];

    float sums[8];
    #pragma unroll
    for (int i = 0; i < 8; i++) sums[i] = 0.0f;

    // Staging swizzle: LDS unit i <- global unit (row=i>>4, u=(i&15)^(row&7)).
    const int gswz = ((t >> 4) << 8) + (((t & 15) ^ ((t >> 4) & 7)) << 4);
    // Read bases: data for (col c, K-seg s) sits at c*256 + (s^(c&7))*16.
    int base_k[4];
    #pragma unroll
    for (int kk = 0; kk < 4; kk++)
        base_k[kk] = lo * 256 + ((((kk << 2) + quad) ^ (lo & 7)) << 4);

    // Stage tile 0 into buf 0.
    {
        const char* g = (const char*)yb + (size_t)c0 * TILEB + gswz;
        #pragma unroll
        for (int q = 0; q < 4; q++)
            __builtin_amdgcn_global_load_lds(AS1C(g + q * 4096),
                                             AS3(&Ys[0][(q * 256 + t) * 16]), 16, 0, 0);
    }
    __syncthreads();

    #pragma unroll
    for (int k = 0; k < NITER; k++) {
        const int ct = c0 + k * NCB;

        // Prefetch tile k+1 into the other buffer (latency hides under MFMA).
        if (k + 1 < NITER) {
            const char* g = (const char*)yb + (size_t)(ct + NCB) * TILEB + gswz;
            #pragma unroll
            for (int q = 0; q < 4; q++)
                __builtin_amdgcn_global_load_lds(AS1C(g + q * 4096),
                                                 AS3(&Ys[(k + 1) & 1][(q * 256 + t) * 16]), 16, 0, 0);
        }

        // Col terms for this tile (fp32).
        float b2[4];
        #pragma unroll
        for (int ci = 0; ci < 4; ci++) b2[ci] = ysq2[ct * CTILE + ci * 16 + lo];

        // Init acc with per-output constant via the MFMA C operand.
        float4v acc[2][4];
        #pragma unroll
        for (int ri = 0; ri < 2; ri++)
            #pragma unroll
            for (int ci = 0; ci < 4; ci++)
                acc[ri][ci] = (float4v){a2v[ri * 4 + 0] + b2[ci], a2v[ri * 4 + 1] + b2[ci],
                                        a2v[ri * 4 + 2] + b2[ci], a2v[ri * 4 + 3] + b2[ci]};

        #pragma unroll
        for (int kk = 0; kk < 4; kk++) {
            #pragma unroll
            for (int ci = 0; ci < 4; ci++) {
                short8 b = *reinterpret_cast<const short8*>(&Ys[k & 1][base_k[kk] + ci * 4096]);
                acc[0][ci] = __builtin_amdgcn_mfma_f32_16x16x32_bf16(af[0][kk], b, acc[0][ci], 0, 0, 0);
                acc[1][ci] = __builtin_amdgcn_mfma_f32_16x16x32_bf16(af[1][kk], b, acc[1][ci], 0, 0, 0);
            }
        }

        // Epilogue: one v_exp_f32 + one add per output (register-only).
        #pragma unroll
        for (int ri = 0; ri < 2; ri++)
            #pragma unroll
            for (int r = 0; r < 4; r++) {
                float s = 0.0f;
                #pragma unroll
                for (int ci = 0; ci < 4; ci++)
                    s += EXP2(acc[ri][ci][r]);
                sums[ri * 4 + r] += s;
            }

        // Single barrier per tile: separates this tile's buf readers from the
        // next DMA write, and drains vmcnt so the prefetched buf is ready.
        __syncthreads();
    }

    // Flush: reduce the 16 lanes sharing each row, one atomicAdd per row.
    #pragma unroll
    for (int i = 0; i < 8; i++) {
        float s = sums[i];
        s += __shfl_xor(s, 1, 64);
        s += __shfl_xor(s, 2, 64);
        s += __shfl_xor(s, 4, 64);
        s += __shfl_xor(s, 8, 64);
        if (lo == 0) {
            int row = rb + w * 32 + (i >> 2) * 16 + quad * 4 + (i & 3);
            atomicAdd(&pl[row], s);
        }
    }
}

// Kernel 3: row losses from accumulated sums -> mean. Single block.
__global__ __launch_bounds__(1024) void finish_kernel(
    const float* __restrict__ pl, const float* __restrict__ diagn,
    float* __restrict__ out)
{
    const int t = threadIdx.x;
    float acc = 0.0f;
    for (int r = t; r < KROWS; r += 1024)
        acc += (log2f(pl[r]) - SHIFT) * LN2_F - diagn[r];
    #pragma unroll
    for (int o = 32; o > 0; o >>= 1) acc += __shfl_down(acc, o, 64);
    __shared__ float ws[16];
    if ((t & 63) == 0) ws[t >> 6] = acc;
    __syncthreads();
    if (t == 0) {
        float s = 0.0f;
        #pragma unroll
        for (int i = 0; i < 16; i++) s += ws[i];
        out[0] = s * (1.0f / KROWS);
    }
}

extern "C" void kernel_launch(void* const* d_in, const int* in_sizes, int n_in,
                              void* d_out, int out_size, void* d_ws, size_t ws_size,
                              hipStream_t stream) {
    const float* x = (const float*)d_in[0];   // features_nc
    const float* y = (const float*)d_in[1];   // features_c
    float* out = (float*)d_out;

    // Workspace layout (~4.2 MB)
    unsigned short* xb = (unsigned short*)d_ws;            // K*D bf16 (2 MB)
    unsigned short* yb = xb + (size_t)KROWS * DDIM;        // K*D bf16 (2 MB)
    float* xsq2  = (float*)(yb + (size_t)KROWS * DDIM);    // K
    float* ysq2  = xsq2 + KROWS;                           // K
    float* diagn = ysq2 + KROWS;                           // K
    float* pl    = diagn + KROWS;                          // K (row sum-of-exp2)

    prep_kernel<<<KROWS / 4, 256, 0, stream>>>(x, y, (unsigned int*)xb, (unsigned int*)yb,
                                               xsq2, ysq2, diagn, pl);
    gemm_lse_kernel<<<64 * NCB, 256, 0, stream>>>(xb, yb, xsq2, ysq2, pl);
    finish_kernel<<<1, 1024, 0, stream>>>(pl, diagn, out);
}

// Round 7
// 88.028 us; speedup vs baseline: 2.2142x; 1.2588x over previous
//
#include <hip/hip_runtime.h>
#include <hip/hip_bf16.h>
#include <math.h>

#define KROWS 8192
#define DDIM  128
#define RT    128            // rows per block (4 waves x 32 rows)
#define CTILE 64             // cols per tile
#define NTILES (KROWS / CTILE)   // 128
#define NCB   16             // col-block count (grid = 64*16 = 1024 = 4/CU)
#define NITER (NTILES / NCB) // 8 tiles per block
#define TILEB (CTILE * DDIM * 2)   // 16384 bytes per Y tile
#define SHIFT 94.0f          // fixed log2-domain shift (logits in [-300,-90])

static constexpr float LOG2E_F = 1.44269504088896340736f;
static constexpr float LN2_F   = 0.69314718055994530942f;

typedef __attribute__((ext_vector_type(8))) short short8;   // 8 bf16
typedef __attribute__((ext_vector_type(4))) float float4v;  // 4 fp32 acc

#if __has_builtin(__builtin_amdgcn_exp2f)
#define EXP2(x) __builtin_amdgcn_exp2f(x)
#else
#define EXP2(x) exp2f(x)
#endif

#define AS1C(p) ((const __attribute__((address_space(1))) void*)(p))
#define AS3(p)  ((__attribute__((address_space(3))) void*)(p))

static __device__ __forceinline__ unsigned short f2bf(float f) {
    __hip_bfloat16 h = __float2bfloat16(f);
    return *reinterpret_cast<unsigned short*>(&h);
}

// Kernel 1: bf16 casts (X pre-scaled by log2e), fp32 row terms, exact fp32
// diagonal logits. One wave per row, 4 rows/block. Also zero-inits pl.
__global__ __launch_bounds__(256) void prep_kernel(
    const float* __restrict__ x, const float* __restrict__ y,
    unsigned int* __restrict__ xb, unsigned int* __restrict__ yb,
    float* __restrict__ xsq2, float* __restrict__ ysq2,
    float* __restrict__ diagn, float* __restrict__ pl)
{
    const int w = threadIdx.x >> 6, lane = threadIdx.x & 63;
    const int row = blockIdx.x * 4 + w;
    if (blockIdx.x < KROWS / 256) pl[blockIdx.x * 256 + threadIdx.x] = 0.0f;
    const float2 xv = *reinterpret_cast<const float2*>(x + (size_t)row * DDIM + lane * 2);
    const float2 yv = *reinterpret_cast<const float2*>(y + (size_t)row * DDIM + lane * 2);
    xb[(size_t)row * 64 + lane] = (unsigned int)f2bf(xv.x * LOG2E_F)
                                | ((unsigned int)f2bf(xv.y * LOG2E_F) << 16);
    yb[(size_t)row * 64 + lane] = (unsigned int)f2bf(yv.x) | ((unsigned int)f2bf(yv.y) << 16);
    float xx = xv.x * xv.x + xv.y * xv.y;
    float yy = yv.x * yv.x + yv.y * yv.y;
    float xy = xv.x * yv.x + xv.y * yv.y;
    #pragma unroll
    for (int o = 32; o > 0; o >>= 1) {
        xx += __shfl_xor(xx, o, 64);
        yy += __shfl_xor(yy, o, 64);
        xy += __shfl_xor(xy, o, 64);
    }
    if (lane == 0) {
        xsq2[row] = fmaf(-0.5f * xx, LOG2E_F, SHIFT);   // log2 row term + shift (fp32)
        ysq2[row] = -0.5f * yy * LOG2E_F;               // log2 col term (fp32)
        diagn[row] = xy - 0.5f * (xx + yy);             // natural-log diag logit (fp32 exact)
    }
}

// Kernel 2: fused bf16 MFMA GEMM + shifted sum-of-exp2.
// Double-buffered LDS; DMA prefetch for tile k+1 issued BEFORE the MFMA phase
// of tile k -> one barrier per tile, DMA latency hidden under compute.
// Tile loop is deliberately ROLLED (#pragma unroll 1) with incremental
// pointers: full unroll hoists 8 iterations of address/ysq2 state, blows the
// 128-VGPR allocator cap (LDS-occupancy-derived) and spills ~80 MB to
// scratch (measured round 6). launch_bounds 2nd arg must stay 2 (rounds 3/5:
// (256,4) -> 64-VGPR cap -> catastrophic spill).
__global__ __launch_bounds__(256, 2) void gemm_lse_kernel(
    const unsigned short* __restrict__ xb, const unsigned short* __restrict__ yb,
    const float* __restrict__ xsq2, const float* __restrict__ ysq2,
    float* __restrict__ pl)
{
    __shared__ alignas(16) unsigned char Ys[2][TILEB];   // 2 x 16 KB, linear (DMA target)

    const int t = threadIdx.x;
    const int w = t >> 6, lane = t & 63, quad = lane >> 4, lo = lane & 15;
    const int rb = (blockIdx.x & 63) * RT;
    const int c0 = blockIdx.x >> 6;    // [0,16)

    // Persistent A fragments (X rows, log2e pre-scaled), from global once.
    short8 af[2][4];
    #pragma unroll
    for (int ri = 0; ri < 2; ri++)
        #pragma unroll
        for (int kk = 0; kk < 4; kk++)
            af[ri][kk] = *reinterpret_cast<const short8*>(
                xb + (size_t)(rb + w * 32 + ri * 16 + lo) * DDIM + kk * 32 + quad * 8);

    // Row terms (log2 domain, SHIFT included).
    float a2v[8];
    #pragma unroll
    for (int ri = 0; ri < 2; ri++)
        #pragma unroll
        for (int r = 0; r < 4; r++)
            a2v[ri * 4 + r] = xsq2[rb + w * 32 + ri * 16 + quad * 4 + r];

    float sums[8];
    #pragma unroll
    for (int i = 0; i < 8; i++) sums[i] = 0.0f;

    // Staging swizzle: LDS unit i <- global unit (row=i>>4, u=(i&15)^(row&7)).
    const int gswz = ((t >> 4) << 8) + (((t & 15) ^ ((t >> 4) & 7)) << 4);
    // Read bases: data for (col c, K-seg s) sits at c*256 + (s^(c&7))*16.
    int base_k[4];
    #pragma unroll
    for (int kk = 0; kk < 4; kk++)
        base_k[kk] = lo * 256 + ((((kk << 2) + quad) ^ (lo & 7)) << 4);

    // Loop-carried pointers (incremental; keeps live state small).
    const char* gp = (const char*)yb + (size_t)c0 * TILEB + gswz;   // this tile
    const float* yp = ysq2 + c0 * CTILE + lo;                        // this tile's col terms

    // Stage tile 0 into buf 0.
    #pragma unroll
    for (int q = 0; q < 4; q++)
        __builtin_amdgcn_global_load_lds(AS1C(gp + q * 4096),
                                         AS3(&Ys[0][(q * 256 + t) * 16]), 16, 0, 0);
    __syncthreads();

    int pb = 0;
    #pragma unroll 1
    for (int k = 0; k < NITER; k++) {
        // Prefetch tile k+1 into the other buffer (latency hides under MFMA).
        if (k + 1 < NITER) {
            const char* gn = gp + NCB * TILEB;
            #pragma unroll
            for (int q = 0; q < 4; q++)
                __builtin_amdgcn_global_load_lds(AS1C(gn + q * 4096),
                                                 AS3(&Ys[pb ^ 1][(q * 256 + t) * 16]), 16, 0, 0);
        }

        // Col terms for this tile (fp32).
        float b2[4];
        #pragma unroll
        for (int ci = 0; ci < 4; ci++) b2[ci] = yp[ci * 16];

        // Init acc with per-output constant via the MFMA C operand.
        float4v acc[2][4];
        #pragma unroll
        for (int ri = 0; ri < 2; ri++)
            #pragma unroll
            for (int ci = 0; ci < 4; ci++)
                acc[ri][ci] = (float4v){a2v[ri * 4 + 0] + b2[ci], a2v[ri * 4 + 1] + b2[ci],
                                        a2v[ri * 4 + 2] + b2[ci], a2v[ri * 4 + 3] + b2[ci]};

        const unsigned char* ysb = Ys[pb];
        #pragma unroll
        for (int kk = 0; kk < 4; kk++) {
            #pragma unroll
            for (int ci = 0; ci < 4; ci++) {
                short8 b = *reinterpret_cast<const short8*>(&ysb[base_k[kk] + ci * 4096]);
                acc[0][ci] = __builtin_amdgcn_mfma_f32_16x16x32_bf16(af[0][kk], b, acc[0][ci], 0, 0, 0);
                acc[1][ci] = __builtin_amdgcn_mfma_f32_16x16x32_bf16(af[1][kk], b, acc[1][ci], 0, 0, 0);
            }
        }

        // Epilogue: one v_exp_f32 + one add per output (register-only).
        #pragma unroll
        for (int ri = 0; ri < 2; ri++)
            #pragma unroll
            for (int r = 0; r < 4; r++) {
                float s = 0.0f;
                #pragma unroll
                for (int ci = 0; ci < 4; ci++)
                    s += EXP2(acc[ri][ci][r]);
                sums[ri * 4 + r] += s;
            }

        gp += NCB * TILEB;
        yp += NCB * CTILE;
        pb ^= 1;

        // Single barrier per tile: separates this tile's buf readers from the
        // next DMA write, and drains vmcnt so the prefetched buf is ready.
        __syncthreads();
    }

    // Flush: reduce the 16 lanes sharing each row, one atomicAdd per row.
    #pragma unroll
    for (int i = 0; i < 8; i++) {
        float s = sums[i];
        s += __shfl_xor(s, 1, 64);
        s += __shfl_xor(s, 2, 64);
        s += __shfl_xor(s, 4, 64);
        s += __shfl_xor(s, 8, 64);
        if (lo == 0) {
            int row = rb + w * 32 + (i >> 2) * 16 + quad * 4 + (i & 3);
            atomicAdd(&pl[row], s);
        }
    }
}

// Kernel 3: row losses from accumulated sums -> mean. Single block.
__global__ __launch_bounds__(1024) void finish_kernel(
    const float* __restrict__ pl, const float* __restrict__ diagn,
    float* __restrict__ out)
{
    const int t = threadIdx.x;
    float acc = 0.0f;
    for (int r = t; r < KROWS; r += 1024)
        acc += (log2f(pl[r]) - SHIFT) * LN2_F - diagn[r];
    #pragma unroll
    for (int o = 32; o > 0; o >>= 1) acc += __shfl_down(acc, o, 64);
    __shared__ float ws[16];
    if ((t & 63) == 0) ws[t >> 6] = acc;
    __syncthreads();
    if (t == 0) {
        float s = 0.0f;
        #pragma unroll
        for (int i = 0; i < 16; i++) s += ws[i];
        out[0] = s * (1.0f / KROWS);
    }
}

extern "C" void kernel_launch(void* const* d_in, const int* in_sizes, int n_in,
                              void* d_out, int out_size, void* d_ws, size_t ws_size,
                              hipStream_t stream) {
    const float* x = (const float*)d_in[0];   // features_nc
    const float* y = (const float*)d_in[1];   // features_c
    float* out = (float*)d_out;

    // Workspace layout (~4.2 MB)
    unsigned short* xb = (unsigned short*)d_ws;            // K*D bf16 (2 MB)
    unsigned short* yb = xb + (size_t)KROWS * DDIM;        // K*D bf16 (2 MB)
    float* xsq2  = (float*)(yb + (size_t)KROWS * DDIM);    // K
    float* ysq2  = xsq2 + KROWS;                           // K
    float* diagn = ysq2 + KROWS;                           // K
    float* pl    = diagn + KROWS;                          // K (row sum-of-exp2)

    prep_kernel<<<KROWS / 4, 256, 0, stream>>>(x, y, (unsigned int*)xb, (unsigned int*)yb,
                                               xsq2, ysq2, diagn, pl);
    gemm_lse_kernel<<<64 * NCB, 256, 0, stream>>>(xb, yb, xsq2, ysq2, pl);
    finish_kernel<<<1, 1024, 0, stream>>>(pl, diagn, out);
}